// Round 1
// baseline (341.232 us; speedup 1.0000x reference)
//
#include <hip/hip_runtime.h>
#include <hip/hip_fp16.h>

typedef _Float16 half8  __attribute__((ext_vector_type(8)));
typedef _Float16 half4_t __attribute__((ext_vector_type(4)));
typedef float    f32x4  __attribute__((ext_vector_type(4)));

#define HDIM  1024
#define BATCH 32
#define TLEN  1024
#define M_TOT (BATCH * TLEN)

#define BM 128
#define BN 128
#define BK 32
#define LDA 40   // padded LDS row stride in halves: 80 B = 5*16 B (b128-aligned, 2-way banks = free)

// ---------------- zero energies ----------------
__global__ void zero_k(float* __restrict__ p) {
    p[blockIdx.x * blockDim.x + threadIdx.x] = 0.f;
}

// ---------------- convert We = W[:, H:] (g-major, k-contiguous) to fp16 ----------------
__global__ void we_convert_k(const float* __restrict__ W, _Float16* __restrict__ We16) {
    int idx = blockIdx.x * blockDim.x + threadIdx.x;      // [0, 1024*1024/4)
    int g  = idx >> 8;                                     // row
    int k4 = idx & 255;                                    // group of 4 within row
    float4 f = *reinterpret_cast<const float4*>(W + (size_t)g * 2048 + 1024 + k4 * 4);
    half4_t h;
    h[0] = (_Float16)f.x; h[1] = (_Float16)f.y; h[2] = (_Float16)f.z; h[3] = (_Float16)f.w;
    *reinterpret_cast<half4_t*>(We16 + (size_t)idx * 4) = h;
}

// ---------------- q[b][g] = bias[g] + sum_h hidden[b][h] * W[g][h]  (fp32, tiny) ----------------
__global__ void qproj_k(const float* __restrict__ hidden, const float* __restrict__ W,
                        const float* __restrict__ bias, float* __restrict__ q) {
    int g = blockIdx.x;
    int t = threadIdx.x;
    int wave = t >> 6, lane = t & 63;
    float acc[BATCH];
#pragma unroll
    for (int b = 0; b < BATCH; b++) acc[b] = 0.f;
    const float* wr = W + (size_t)g * 2048;
    for (int h = t; h < HDIM; h += 256) {
        float w = wr[h];
#pragma unroll
        for (int b = 0; b < BATCH; b++) acc[b] = fmaf(w, hidden[b * HDIM + h], acc[b]);
    }
    __shared__ float sm[4 * BATCH];
#pragma unroll
    for (int b = 0; b < BATCH; b++) {
        float s = acc[b];
#pragma unroll
        for (int off = 32; off >= 1; off >>= 1) s += __shfl_xor(s, off);
        if (lane == 0) sm[wave * BATCH + b] = s;
    }
    __syncthreads();
    if (t < BATCH) {
        float s = sm[t] + sm[BATCH + t] + sm[2 * BATCH + t] + sm[3 * BATCH + t];
        q[t * HDIM + g] = s + bias[g];
    }
}

// ---------------- fused GEMM + tanh + v-dot: energies[m] += sum_g v[g]*tanh(q[b][g] + enc[m]·We[g]) ----
__global__ __launch_bounds__(256, 2)
void attn_gemm_k(const float* __restrict__ enc, const _Float16* __restrict__ We16,
                 const float* __restrict__ q, const float* __restrict__ v,
                 float* __restrict__ energies) {
    __shared__ _Float16 As[BM * LDA];
    __shared__ _Float16 Bs[BN * LDA];

    const int tid  = threadIdx.x;
    const int n0   = blockIdx.x * BN;     // n fast-varying: 8 blocks share an A stripe (L2 reuse)
    const int m0   = blockIdx.y * BM;
    const int wave = tid >> 6;
    const int lane = tid & 63;
    const int quad = lane >> 4;
    const int l16  = lane & 15;
    const int wm   = (wave & 1) * 64;
    const int wn   = (wave >> 1) * 64;

    // staging map: thread -> (row = tid>>1, 16-half segment = (tid&1)*16)
    const int srow = tid >> 1;
    const int scol = (tid & 1) * 16;

    f32x4 acc[4][4];
#pragma unroll
    for (int i = 0; i < 4; i++)
#pragma unroll
        for (int j = 0; j < 4; j++) acc[i][j] = {0.f, 0.f, 0.f, 0.f};

    const float*    ag = enc  + (size_t)(m0 + srow) * HDIM + scol;
    const _Float16* bg = We16 + (size_t)(n0 + srow) * HDIM + scol;
    _Float16* aw = &As[srow * LDA + scol];
    _Float16* bw = &Bs[srow * LDA + scol];

    for (int k0 = 0; k0 < HDIM; k0 += BK) {
        // global loads: A 16 floats (fp32), B 16 halves
        float4 a0 = *reinterpret_cast<const float4*>(ag + k0 + 0);
        float4 a1 = *reinterpret_cast<const float4*>(ag + k0 + 4);
        float4 a2 = *reinterpret_cast<const float4*>(ag + k0 + 8);
        float4 a3 = *reinterpret_cast<const float4*>(ag + k0 + 12);
        float4 b0 = *reinterpret_cast<const float4*>(bg + k0);       // 8 halves
        float4 b1 = *reinterpret_cast<const float4*>(bg + k0 + 8);   // 8 halves

        __syncthreads();   // previous iter's LDS reads done before overwrite

        half8 ha0, ha1;
        ha0[0] = (_Float16)a0.x; ha0[1] = (_Float16)a0.y; ha0[2] = (_Float16)a0.z; ha0[3] = (_Float16)a0.w;
        ha0[4] = (_Float16)a1.x; ha0[5] = (_Float16)a1.y; ha0[6] = (_Float16)a1.z; ha0[7] = (_Float16)a1.w;
        ha1[0] = (_Float16)a2.x; ha1[1] = (_Float16)a2.y; ha1[2] = (_Float16)a2.z; ha1[3] = (_Float16)a2.w;
        ha1[4] = (_Float16)a3.x; ha1[5] = (_Float16)a3.y; ha1[6] = (_Float16)a3.z; ha1[7] = (_Float16)a3.w;
        *reinterpret_cast<half8*>(aw)     = ha0;
        *reinterpret_cast<half8*>(aw + 8) = ha1;
        *reinterpret_cast<float4*>(bw)     = b0;
        *reinterpret_cast<float4*>(bw + 8) = b1;

        __syncthreads();

        // fragments: A[m=l16][k=quad*8+j], B[n=l16][k=quad*8+j]
        half8 af[4], bf[4];
#pragma unroll
        for (int i = 0; i < 4; i++) {
            af[i] = *reinterpret_cast<const half8*>(&As[(wm + i * 16 + l16) * LDA + quad * 8]);
            bf[i] = *reinterpret_cast<const half8*>(&Bs[(wn + i * 16 + l16) * LDA + quad * 8]);
        }
#pragma unroll
        for (int mi = 0; mi < 4; mi++)
#pragma unroll
            for (int ni = 0; ni < 4; ni++)
                acc[mi][ni] = __builtin_amdgcn_mfma_f32_16x16x32_f16(af[mi], bf[ni], acc[mi][ni], 0, 0, 0);
    }

    // epilogue: C/D layout col = l16, row = quad*4 + r
    const int bidx = m0 >> 10;   // BM=128 divides T=1024, so batch index uniform per block
    float qv[4], vv[4];
#pragma unroll
    for (int ni = 0; ni < 4; ni++) {
        int g = n0 + wn + ni * 16 + l16;
        qv[ni] = q[bidx * HDIM + g];
        vv[ni] = v[g];
    }
#pragma unroll
    for (int mi = 0; mi < 4; mi++) {
#pragma unroll
        for (int r = 0; r < 4; r++) {
            int row = wm + mi * 16 + quad * 4 + r;
            float s = 0.f;
#pragma unroll
            for (int ni = 0; ni < 4; ni++) {
                float pre = acc[mi][ni][r] + qv[ni];
                float e = __expf(2.f * pre);          // tanh(x) = 1 - 2/(e^{2x}+1); saturates correctly
                float th = 1.f - 2.f / (e + 1.f);
                s = fmaf(th, vv[ni], s);
            }
            // butterfly over the 16 column-lanes (same row)
            s += __shfl_xor(s, 1);
            s += __shfl_xor(s, 2);
            s += __shfl_xor(s, 4);
            s += __shfl_xor(s, 8);
            if (l16 == 0) atomicAdd(&energies[m0 + row], s);
        }
    }
}

// ---------------- softmax over t per batch row ----------------
__global__ void softmax_k(const float* __restrict__ energies, float* __restrict__ out) {
    int b = blockIdx.x;
    int t = threadIdx.x;
    int wave = t >> 6, lane = t & 63;
    __shared__ float smax[4], ssum[4];
    float e[4];
#pragma unroll
    for (int i = 0; i < 4; i++) e[i] = energies[b * TLEN + t + i * 256];
    float m = fmaxf(fmaxf(e[0], e[1]), fmaxf(e[2], e[3]));
#pragma unroll
    for (int off = 32; off >= 1; off >>= 1) m = fmaxf(m, __shfl_xor(m, off));
    if (lane == 0) smax[wave] = m;
    __syncthreads();
    float M = fmaxf(fmaxf(smax[0], smax[1]), fmaxf(smax[2], smax[3]));
    float x[4]; float s = 0.f;
#pragma unroll
    for (int i = 0; i < 4; i++) { x[i] = __expf(e[i] - M); s += x[i]; }
#pragma unroll
    for (int off = 32; off >= 1; off >>= 1) s += __shfl_xor(s, off);
    if (lane == 0) ssum[wave] = s;
    __syncthreads();
    float S = ssum[0] + ssum[1] + ssum[2] + ssum[3];
    float inv = 1.f / S;
#pragma unroll
    for (int i = 0; i < 4; i++) out[b * TLEN + t + i * 256] = x[i] * inv;
}

extern "C" void kernel_launch(void* const* d_in, const int* in_sizes, int n_in,
                              void* d_out, int out_size, void* d_ws, size_t ws_size,
                              hipStream_t stream) {
    const float* hidden = (const float*)d_in[0];   // (1, 32, 1024) fp32
    const float* enc    = (const float*)d_in[1];   // (32, 1024, 1024) fp32
    const float* W      = (const float*)d_in[2];   // (1024, 2048) fp32
    const float* bias   = (const float*)d_in[3];   // (1024,) fp32
    const float* v      = (const float*)d_in[4];   // (1024,) fp32
    float* out = (float*)d_out;                    // (32, 1, 1024) fp32

    char* ws = (char*)d_ws;
    float*    q     = (float*)ws;                  // 32*1024 fp32   = 128 KB
    float*    energ = (float*)(ws + 131072);       // 32768 fp32     = 128 KB
    _Float16* We16  = (_Float16*)(ws + 262144);    // 1024*1024 fp16 = 2 MB

    zero_k<<<dim3(M_TOT / 256), 256, 0, stream>>>(energ);
    we_convert_k<<<dim3(1024), 256, 0, stream>>>(W, We16);
    qproj_k<<<dim3(HDIM), 256, 0, stream>>>(hidden, W, bias, q);
    attn_gemm_k<<<dim3(8, 256), 256, 0, stream>>>(enc, We16, q, v, energ);
    softmax_k<<<dim3(BATCH), 256, 0, stream>>>(energ, out);
}

// Round 2
// 324.742 us; speedup vs baseline: 1.0508x; 1.0508x over previous
//
#include <hip/hip_runtime.h>
#include <hip/hip_fp16.h>

typedef _Float16 half8   __attribute__((ext_vector_type(8)));
typedef _Float16 half4_t __attribute__((ext_vector_type(4)));
typedef float    f32x4   __attribute__((ext_vector_type(4)));

#define HDIM  1024
#define BATCH 32
#define TLEN  1024
#define M_TOT (BATCH * TLEN)

#define BM 128
#define BN 128
#define BK 32
#define LDA 40   // fallback-path padded LDS stride (halves)

// ---------------- zero energies ----------------
__global__ void zero_k(float* __restrict__ p) {
    p[blockIdx.x * blockDim.x + threadIdx.x] = 0.f;
}

// ---------------- convert We = W[:, H:] to fp16 (g-major, k-contiguous) ----------------
__global__ void we_convert_k(const float* __restrict__ W, _Float16* __restrict__ We16) {
    int idx = blockIdx.x * blockDim.x + threadIdx.x;      // [0, 1024*1024/4)
    int g  = idx >> 8;
    int k4 = idx & 255;
    float4 f = *reinterpret_cast<const float4*>(W + (size_t)g * 2048 + 1024 + k4 * 4);
    half4_t h;
    h[0] = (_Float16)f.x; h[1] = (_Float16)f.y; h[2] = (_Float16)f.z; h[3] = (_Float16)f.w;
    *reinterpret_cast<half4_t*>(We16 + (size_t)idx * 4) = h;
}

// ---------------- convert enc (32M fp32) to fp16 ----------------
__global__ void enc_convert_k(const float* __restrict__ enc, _Float16* __restrict__ enc16) {
    size_t i = ((size_t)blockIdx.x * blockDim.x + threadIdx.x) * 8;
    float4 f0 = *reinterpret_cast<const float4*>(enc + i);
    float4 f1 = *reinterpret_cast<const float4*>(enc + i + 4);
    half8 h;
    h[0] = (_Float16)f0.x; h[1] = (_Float16)f0.y; h[2] = (_Float16)f0.z; h[3] = (_Float16)f0.w;
    h[4] = (_Float16)f1.x; h[5] = (_Float16)f1.y; h[6] = (_Float16)f1.z; h[7] = (_Float16)f1.w;
    *reinterpret_cast<half8*>(enc16 + i) = h;
}

// ---------------- q[b][g] = bias[g] + sum_h hidden[b][h] * W[g][h] ----------------
__global__ void qproj_k(const float* __restrict__ hidden, const float* __restrict__ W,
                        const float* __restrict__ bias, float* __restrict__ q) {
    int g = blockIdx.x;
    int t = threadIdx.x;
    int wave = t >> 6, lane = t & 63;
    float acc[BATCH];
#pragma unroll
    for (int b = 0; b < BATCH; b++) acc[b] = 0.f;
    const float* wr = W + (size_t)g * 2048;
    for (int h = t; h < HDIM; h += 256) {
        float w = wr[h];
#pragma unroll
        for (int b = 0; b < BATCH; b++) acc[b] = fmaf(w, hidden[b * HDIM + h], acc[b]);
    }
    __shared__ float sm[4 * BATCH];
#pragma unroll
    for (int b = 0; b < BATCH; b++) {
        float s = acc[b];
#pragma unroll
        for (int off = 32; off >= 1; off >>= 1) s += __shfl_xor(s, off);
        if (lane == 0) sm[wave * BATCH + b] = s;
    }
    __syncthreads();
    if (t < BATCH) {
        float s = sm[t] + sm[BATCH + t] + sm[2 * BATCH + t] + sm[3 * BATCH + t];
        q[t * HDIM + g] = s + bias[g];
    }
}

__device__ __forceinline__ void async16(const void* g, void* l) {
    __builtin_amdgcn_global_load_lds(
        (const __attribute__((address_space(1))) void*)g,
        (__attribute__((address_space(3))) void*)l, 16, 0, 0);
}

// ---------------- FAST: fp16 A/B, global_load_lds staging (m97 structure) ----------------
// grid (256, 8): m on x so the 8 n-blocks of a stripe share linearID%8 -> same XCD L2
__global__ void attn_gemm_lds_k(const _Float16* __restrict__ enc16,
                                const _Float16* __restrict__ We16,
                                const float* __restrict__ q, const float* __restrict__ v,
                                float* __restrict__ energies) {
    __shared__ _Float16 As[BM * BK];   // 8 KB, unpadded (global_load_lds lane-ordered)
    __shared__ _Float16 Bs[BN * BK];   // 8 KB

    const int tid  = threadIdx.x;
    const int m0   = blockIdx.x * BM;
    const int n0   = blockIdx.y * BN;
    const int wave = tid >> 6;
    const int lane = tid & 63;
    const int quad = lane >> 4;
    const int l16  = lane & 15;
    const int wm   = (wave & 1) * 64;
    const int wn   = (wave >> 1) * 64;

    f32x4 acc[4][4];
#pragma unroll
    for (int i = 0; i < 4; i++)
#pragma unroll
        for (int j = 0; j < 4; j++) acc[i][j] = {0.f, 0.f, 0.f, 0.f};

    // staging map: flat byte f = issue*4096 + wave*1024 + lane*16 over a 128x32h tile
    // row = issue*64 + wave*16 + (lane>>2), col(halves) = (lane&3)*8
    const int arow = wave * 16 + (lane >> 2);
    const int acol = (lane & 3) * 8;
    const _Float16* gA = enc16 + (size_t)(m0 + arow) * HDIM + acol;
    const _Float16* gB = We16  + (size_t)(n0 + arow) * HDIM + acol;
    _Float16* lA = As + wave * 512;   // + issue*2048 halves
    _Float16* lB = Bs + wave * 512;
    const size_t gstep = (size_t)64 * HDIM;   // issue-1 global offset (64 rows)

    for (int k0 = 0; k0 < HDIM; k0 += BK) {
        __syncthreads();                       // prev iter frag reads done
        async16(gA + k0, lA);
        async16(gA + k0 + gstep, lA + 2048);
        async16(gB + k0, lB);
        async16(gB + k0 + gstep, lB + 2048);
        __syncthreads();                       // drains vmcnt -> LDS valid

        half8 af[4], bf[4];
#pragma unroll
        for (int i = 0; i < 4; i++) {
            af[i] = *reinterpret_cast<const half8*>(&As[(wm + i * 16 + l16) * BK + quad * 8]);
            bf[i] = *reinterpret_cast<const half8*>(&Bs[(wn + i * 16 + l16) * BK + quad * 8]);
        }
#pragma unroll
        for (int mi = 0; mi < 4; mi++)
#pragma unroll
            for (int ni = 0; ni < 4; ni++)
                acc[mi][ni] = __builtin_amdgcn_mfma_f32_16x16x32_f16(af[mi], bf[ni], acc[mi][ni], 0, 0, 0);
    }

    // epilogue: C/D col = l16, row = quad*4 + r
    const int bidx = m0 >> 10;
    float qv[4], vv[4];
#pragma unroll
    for (int ni = 0; ni < 4; ni++) {
        int g = n0 + wn + ni * 16 + l16;
        qv[ni] = q[bidx * HDIM + g];
        vv[ni] = v[g];
    }
#pragma unroll
    for (int mi = 0; mi < 4; mi++) {
#pragma unroll
        for (int r = 0; r < 4; r++) {
            int row = wm + mi * 16 + quad * 4 + r;
            float s = 0.f;
#pragma unroll
            for (int ni = 0; ni < 4; ni++) {
                float pre = acc[mi][ni][r] + qv[ni];
                float e = __expf(2.f * pre);
                float th = 1.f - 2.f / (e + 1.f);
                s = fmaf(th, vv[ni], s);
            }
            s += __shfl_xor(s, 1);
            s += __shfl_xor(s, 2);
            s += __shfl_xor(s, 4);
            s += __shfl_xor(s, 8);
            if (l16 == 0) atomicAdd(&energies[m0 + row], s);
        }
    }
}

// ---------------- FALLBACK: fp32 A on-the-fly convert (R1 kernel, regridded) ----------------
__global__ __launch_bounds__(256, 2)
void attn_gemm_k(const float* __restrict__ enc, const _Float16* __restrict__ We16,
                 const float* __restrict__ q, const float* __restrict__ v,
                 float* __restrict__ energies) {
    __shared__ _Float16 As[BM * LDA];
    __shared__ _Float16 Bs[BN * LDA];

    const int tid  = threadIdx.x;
    const int m0   = blockIdx.x * BM;
    const int n0   = blockIdx.y * BN;
    const int wave = tid >> 6;
    const int lane = tid & 63;
    const int quad = lane >> 4;
    const int l16  = lane & 15;
    const int wm   = (wave & 1) * 64;
    const int wn   = (wave >> 1) * 64;

    const int srow = tid >> 1;
    const int scol = (tid & 1) * 16;

    f32x4 acc[4][4];
#pragma unroll
    for (int i = 0; i < 4; i++)
#pragma unroll
        for (int j = 0; j < 4; j++) acc[i][j] = {0.f, 0.f, 0.f, 0.f};

    const float*    ag = enc  + (size_t)(m0 + srow) * HDIM + scol;
    const _Float16* bg = We16 + (size_t)(n0 + srow) * HDIM + scol;
    _Float16* aw = &As[srow * LDA + scol];
    _Float16* bw = &Bs[srow * LDA + scol];

    for (int k0 = 0; k0 < HDIM; k0 += BK) {
        float4 a0 = *reinterpret_cast<const float4*>(ag + k0 + 0);
        float4 a1 = *reinterpret_cast<const float4*>(ag + k0 + 4);
        float4 a2 = *reinterpret_cast<const float4*>(ag + k0 + 8);
        float4 a3 = *reinterpret_cast<const float4*>(ag + k0 + 12);
        float4 b0 = *reinterpret_cast<const float4*>(bg + k0);
        float4 b1 = *reinterpret_cast<const float4*>(bg + k0 + 8);

        __syncthreads();

        half8 ha0, ha1;
        ha0[0] = (_Float16)a0.x; ha0[1] = (_Float16)a0.y; ha0[2] = (_Float16)a0.z; ha0[3] = (_Float16)a0.w;
        ha0[4] = (_Float16)a1.x; ha0[5] = (_Float16)a1.y; ha0[6] = (_Float16)a1.z; ha0[7] = (_Float16)a1.w;
        ha1[0] = (_Float16)a2.x; ha1[1] = (_Float16)a2.y; ha1[2] = (_Float16)a2.z; ha1[3] = (_Float16)a2.w;
        ha1[4] = (_Float16)a3.x; ha1[5] = (_Float16)a3.y; ha1[6] = (_Float16)a3.z; ha1[7] = (_Float16)a3.w;
        *reinterpret_cast<half8*>(aw)     = ha0;
        *reinterpret_cast<half8*>(aw + 8) = ha1;
        *reinterpret_cast<float4*>(bw)     = b0;
        *reinterpret_cast<float4*>(bw + 8) = b1;

        __syncthreads();

        half8 af[4], bf[4];
#pragma unroll
        for (int i = 0; i < 4; i++) {
            af[i] = *reinterpret_cast<const half8*>(&As[(wm + i * 16 + l16) * LDA + quad * 8]);
            bf[i] = *reinterpret_cast<const half8*>(&Bs[(wn + i * 16 + l16) * LDA + quad * 8]);
        }
#pragma unroll
        for (int mi = 0; mi < 4; mi++)
#pragma unroll
            for (int ni = 0; ni < 4; ni++)
                acc[mi][ni] = __builtin_amdgcn_mfma_f32_16x16x32_f16(af[mi], bf[ni], acc[mi][ni], 0, 0, 0);
    }

    const int bidx = m0 >> 10;
    float qv[4], vv[4];
#pragma unroll
    for (int ni = 0; ni < 4; ni++) {
        int g = n0 + wn + ni * 16 + l16;
        qv[ni] = q[bidx * HDIM + g];
        vv[ni] = v[g];
    }
#pragma unroll
    for (int mi = 0; mi < 4; mi++) {
#pragma unroll
        for (int r = 0; r < 4; r++) {
            int row = wm + mi * 16 + quad * 4 + r;
            float s = 0.f;
#pragma unroll
            for (int ni = 0; ni < 4; ni++) {
                float pre = acc[mi][ni][r] + qv[ni];
                float e = __expf(2.f * pre);
                float th = 1.f - 2.f / (e + 1.f);
                s = fmaf(th, vv[ni], s);
            }
            s += __shfl_xor(s, 1);
            s += __shfl_xor(s, 2);
            s += __shfl_xor(s, 4);
            s += __shfl_xor(s, 8);
            if (l16 == 0) atomicAdd(&energies[m0 + row], s);
        }
    }
}

// ---------------- softmax over t per batch row ----------------
__global__ void softmax_k(const float* __restrict__ energies, float* __restrict__ out) {
    int b = blockIdx.x;
    int t = threadIdx.x;
    int wave = t >> 6, lane = t & 63;
    __shared__ float smax[4], ssum[4];
    float e[4];
#pragma unroll
    for (int i = 0; i < 4; i++) e[i] = energies[b * TLEN + t + i * 256];
    float m = fmaxf(fmaxf(e[0], e[1]), fmaxf(e[2], e[3]));
#pragma unroll
    for (int off = 32; off >= 1; off >>= 1) m = fmaxf(m, __shfl_xor(m, off));
    if (lane == 0) smax[wave] = m;
    __syncthreads();
    float M = fmaxf(fmaxf(smax[0], smax[1]), fmaxf(smax[2], smax[3]));
    float x[4]; float s = 0.f;
#pragma unroll
    for (int i = 0; i < 4; i++) { x[i] = __expf(e[i] - M); s += x[i]; }
#pragma unroll
    for (int off = 32; off >= 1; off >>= 1) s += __shfl_xor(s, off);
    if (lane == 0) ssum[wave] = s;
    __syncthreads();
    float S = ssum[0] + ssum[1] + ssum[2] + ssum[3];
    float inv = 1.f / S;
#pragma unroll
    for (int i = 0; i < 4; i++) out[b * TLEN + t + i * 256] = x[i] * inv;
}

extern "C" void kernel_launch(void* const* d_in, const int* in_sizes, int n_in,
                              void* d_out, int out_size, void* d_ws, size_t ws_size,
                              hipStream_t stream) {
    const float* hidden = (const float*)d_in[0];   // (1, 32, 1024) fp32
    const float* enc    = (const float*)d_in[1];   // (32, 1024, 1024) fp32
    const float* W      = (const float*)d_in[2];   // (1024, 2048) fp32
    const float* bias   = (const float*)d_in[3];   // (1024,) fp32
    const float* v      = (const float*)d_in[4];   // (1024,) fp32
    float* out = (float*)d_out;                    // (32, 1, 1024) fp32

    char* ws = (char*)d_ws;
    float*    q     = (float*)ws;                  // 128 KB
    float*    energ = (float*)(ws + 131072);       // 128 KB
    _Float16* We16  = (_Float16*)(ws + 262144);    // 2 MB
    _Float16* enc16 = (_Float16*)(ws + 262144 + 2097152);  // 64 MB
    const size_t need_fast = 262144 + 2097152 + (size_t)M_TOT * HDIM * 2;  // ~66.3 MB

    zero_k<<<dim3(M_TOT / 256), 256, 0, stream>>>(energ);
    we_convert_k<<<dim3(1024), 256, 0, stream>>>(W, We16);
    qproj_k<<<dim3(HDIM), 256, 0, stream>>>(hidden, W, bias, q);
    if (ws_size >= need_fast) {
        enc_convert_k<<<dim3((size_t)M_TOT * HDIM / 8 / 256), 256, 0, stream>>>(enc, enc16);
        attn_gemm_lds_k<<<dim3(256, 8), 256, 0, stream>>>(enc16, We16, q, v, energ);
    } else {
        attn_gemm_k<<<dim3(256, 8), 256, 0, stream>>>(enc, We16, q, v, energ);
    }
    softmax_k<<<dim3(BATCH), 256, 0, stream>>>(energ, out);
}

// Round 3
// 317.616 us; speedup vs baseline: 1.0744x; 1.0224x over previous
//
#include <hip/hip_runtime.h>
#include <hip/hip_fp16.h>

typedef _Float16 half8   __attribute__((ext_vector_type(8)));
typedef _Float16 half4_t __attribute__((ext_vector_type(4)));
typedef float    f32x4   __attribute__((ext_vector_type(4)));

#define HDIM  1024
#define BATCH 32
#define TLEN  1024
#define M_TOT (BATCH * TLEN)

#define BM 128
#define BN 128
#define BKF 64   // fast-path K-tile (halves); row = 128 B
#define LDA 40   // fallback-path padded LDS stride (halves)

// ---------------- zero energies ----------------
__global__ void zero_k(float* __restrict__ p) {
    p[blockIdx.x * blockDim.x + threadIdx.x] = 0.f;
}

// ---------------- convert We = W[:, H:] to fp16 (g-major, k-contiguous) ----------------
__global__ void we_convert_k(const float* __restrict__ W, _Float16* __restrict__ We16) {
    int idx = blockIdx.x * blockDim.x + threadIdx.x;      // [0, 1024*1024/4)
    int g  = idx >> 8;
    int k4 = idx & 255;
    float4 f = *reinterpret_cast<const float4*>(W + (size_t)g * 2048 + 1024 + k4 * 4);
    half4_t h;
    h[0] = (_Float16)f.x; h[1] = (_Float16)f.y; h[2] = (_Float16)f.z; h[3] = (_Float16)f.w;
    *reinterpret_cast<half4_t*>(We16 + (size_t)idx * 4) = h;
}

// ---------------- convert enc (32M fp32) to fp16 ----------------
__global__ void enc_convert_k(const float* __restrict__ enc, _Float16* __restrict__ enc16) {
    size_t i = ((size_t)blockIdx.x * blockDim.x + threadIdx.x) * 8;
    float4 f0 = *reinterpret_cast<const float4*>(enc + i);
    float4 f1 = *reinterpret_cast<const float4*>(enc + i + 4);
    half8 h;
    h[0] = (_Float16)f0.x; h[1] = (_Float16)f0.y; h[2] = (_Float16)f0.z; h[3] = (_Float16)f0.w;
    h[4] = (_Float16)f1.x; h[5] = (_Float16)f1.y; h[6] = (_Float16)f1.z; h[7] = (_Float16)f1.w;
    *reinterpret_cast<half8*>(enc16 + i) = h;
}

// ---------------- q[b][g] = bias[g] + sum_h hidden[b][h] * W[g][h] ----------------
__global__ void qproj_k(const float* __restrict__ hidden, const float* __restrict__ W,
                        const float* __restrict__ bias, float* __restrict__ q) {
    int g = blockIdx.x;
    int t = threadIdx.x;
    int wave = t >> 6, lane = t & 63;
    float acc[BATCH];
#pragma unroll
    for (int b = 0; b < BATCH; b++) acc[b] = 0.f;
    const float* wr = W + (size_t)g * 2048;
    for (int h = t; h < HDIM; h += 256) {
        float w = wr[h];
#pragma unroll
        for (int b = 0; b < BATCH; b++) acc[b] = fmaf(w, hidden[b * HDIM + h], acc[b]);
    }
    __shared__ float sm[4 * BATCH];
#pragma unroll
    for (int b = 0; b < BATCH; b++) {
        float s = acc[b];
#pragma unroll
        for (int off = 32; off >= 1; off >>= 1) s += __shfl_xor(s, off);
        if (lane == 0) sm[wave * BATCH + b] = s;
    }
    __syncthreads();
    if (t < BATCH) {
        float s = sm[t] + sm[BATCH + t] + sm[2 * BATCH + t] + sm[3 * BATCH + t];
        q[t * HDIM + g] = s + bias[g];
    }
}

__device__ __forceinline__ void async16(const void* g, void* l) {
    __builtin_amdgcn_global_load_lds(
        (const __attribute__((address_space(1))) void*)g,
        (__attribute__((address_space(3))) void*)l, 16, 0, 0);
}

// ---------------- FAST: BK=64, XOR-swizzled LDS, issue-early pipeline ----------------
// grid (256, 8): m on x so the 8 n-blocks sharing an A stripe land on the same XCD
__global__ __launch_bounds__(256)
void attn_gemm_lds_k(const _Float16* __restrict__ enc16,
                     const _Float16* __restrict__ We16,
                     const float* __restrict__ q, const float* __restrict__ v,
                     float* __restrict__ energies) {
    __shared__ _Float16 As[BM * BKF];   // 16 KB, rows of 128 B, chunks XOR-swizzled
    __shared__ _Float16 Bs[BN * BKF];   // 16 KB

    const int tid  = threadIdx.x;
    const int m0   = blockIdx.x * BM;
    const int n0   = blockIdx.y * BN;
    const int wave = tid >> 6;
    const int lane = tid & 63;
    const int quad = lane >> 4;
    const int l16  = lane & 15;
    const int wm   = (wave & 1) * 64;
    const int wn   = (wave >> 1) * 64;

    f32x4 acc[4][4];
#pragma unroll
    for (int i = 0; i < 4; i++)
#pragma unroll
        for (int j = 0; j < 4; j++) acc[i][j] = {0.f, 0.f, 0.f, 0.f};

    // ---- staging map (per 128x64h tile = 16 KB = 16 issues of 1 KB; 4 issues/wave/matrix)
    // issue ii: row = wave*32 + ii*8 + (lane>>3); fetched chunk c = (lane&7) ^ (lane>>3)
    // (placement chunk c' = lane&7 at LDS row*128B, so stored c' = c ^ (row&7); row&7 == lane>>3)
    const int srow = wave * 32 + (lane >> 3);
    const int scol = ((lane & 7) ^ (lane >> 3)) * 8;          // halves
    const _Float16* gA = enc16 + (size_t)(m0 + srow) * HDIM + scol;
    const _Float16* gB = We16  + (size_t)(n0 + srow) * HDIM + scol;
    _Float16* lA = As + wave * 2048;   // + ii*512 halves per issue
    _Float16* lB = Bs + wave * 2048;
    const size_t istep = (size_t)8 * HDIM;   // 8 rows per issue

    // ---- preload tile k0 = 0
#pragma unroll
    for (int ii = 0; ii < 4; ii++) {
        async16(gA + ii * istep, lA + ii * 512);
        async16(gB + ii * istep, lB + ii * 512);
    }
    __syncthreads();   // drain vmcnt -> tile 0 valid

    // ---- frag read offsets (loop-invariant): row r, want chunk c=s*4+quad stored at c^(r&7)
    int aoff[2][4], boff[2][4];
#pragma unroll
    for (int s = 0; s < 2; s++)
#pragma unroll
        for (int i = 0; i < 4; i++) {
            int ra = wm + i * 16 + l16;
            int rb = wn + i * 16 + l16;
            aoff[s][i] = ra * BKF + (((s * 4 + quad) ^ (l16 & 7)) * 8);
            boff[s][i] = rb * BKF + (((s * 4 + quad) ^ (l16 & 7)) * 8);
        }

    for (int k0 = 0; k0 < HDIM; k0 += BKF) {
        // read ALL frags for this tile into registers
        half8 af[2][4], bf[2][4];
#pragma unroll
        for (int s = 0; s < 2; s++)
#pragma unroll
            for (int i = 0; i < 4; i++) {
                af[s][i] = *reinterpret_cast<const half8*>(&As[aoff[s][i]]);
                bf[s][i] = *reinterpret_cast<const half8*>(&Bs[boff[s][i]]);
            }
        __syncthreads();   // all waves done reading LDS (lgkm drained by compiler)

        // issue next tile's loads NOW -> latency overlaps the MFMA below
        if (k0 + BKF < HDIM) {
            const int kn = k0 + BKF;
#pragma unroll
            for (int ii = 0; ii < 4; ii++) {
                async16(gA + kn + ii * istep, lA + ii * 512);
                async16(gB + kn + ii * istep, lB + ii * 512);
            }
        }

#pragma unroll
        for (int s = 0; s < 2; s++)
#pragma unroll
            for (int mi = 0; mi < 4; mi++)
#pragma unroll
                for (int ni = 0; ni < 4; ni++)
                    acc[mi][ni] = __builtin_amdgcn_mfma_f32_16x16x32_f16(af[s][mi], bf[s][ni], acc[mi][ni], 0, 0, 0);

        __syncthreads();   // drains vmcnt -> next tile valid
    }

    // epilogue: C/D col = l16, row = quad*4 + r
    const int bidx = m0 >> 10;
    float qv[4], vv[4];
#pragma unroll
    for (int ni = 0; ni < 4; ni++) {
        int g = n0 + wn + ni * 16 + l16;
        qv[ni] = q[bidx * HDIM + g];
        vv[ni] = v[g];
    }
#pragma unroll
    for (int mi = 0; mi < 4; mi++) {
#pragma unroll
        for (int r = 0; r < 4; r++) {
            int row = wm + mi * 16 + quad * 4 + r;
            float s = 0.f;
#pragma unroll
            for (int ni = 0; ni < 4; ni++) {
                float pre = acc[mi][ni][r] + qv[ni];
                float e = __expf(2.f * pre);
                float th = 1.f - 2.f / (e + 1.f);
                s = fmaf(th, vv[ni], s);
            }
            s += __shfl_xor(s, 1);
            s += __shfl_xor(s, 2);
            s += __shfl_xor(s, 4);
            s += __shfl_xor(s, 8);
            if (l16 == 0) atomicAdd(&energies[m0 + row], s);
        }
    }
}

// ---------------- FALLBACK: fp32 A on-the-fly convert (BK=32, padded LDS) ----------------
__global__ __launch_bounds__(256, 2)
void attn_gemm_k(const float* __restrict__ enc, const _Float16* __restrict__ We16,
                 const float* __restrict__ q, const float* __restrict__ v,
                 float* __restrict__ energies) {
    __shared__ _Float16 As[BM * LDA];
    __shared__ _Float16 Bs[BN * LDA];

    const int tid  = threadIdx.x;
    const int m0   = blockIdx.x * BM;
    const int n0   = blockIdx.y * BN;
    const int wave = tid >> 6;
    const int lane = tid & 63;
    const int quad = lane >> 4;
    const int l16  = lane & 15;
    const int wm   = (wave & 1) * 64;
    const int wn   = (wave >> 1) * 64;

    const int srow = tid >> 1;
    const int scol = (tid & 1) * 16;

    f32x4 acc[4][4];
#pragma unroll
    for (int i = 0; i < 4; i++)
#pragma unroll
        for (int j = 0; j < 4; j++) acc[i][j] = {0.f, 0.f, 0.f, 0.f};

    const float*    ag = enc  + (size_t)(m0 + srow) * HDIM + scol;
    const _Float16* bg = We16 + (size_t)(n0 + srow) * HDIM + scol;
    _Float16* aw = &As[srow * LDA + scol];
    _Float16* bw = &Bs[srow * LDA + scol];

    for (int k0 = 0; k0 < HDIM; k0 += 32) {
        float4 a0 = *reinterpret_cast<const float4*>(ag + k0 + 0);
        float4 a1 = *reinterpret_cast<const float4*>(ag + k0 + 4);
        float4 a2 = *reinterpret_cast<const float4*>(ag + k0 + 8);
        float4 a3 = *reinterpret_cast<const float4*>(ag + k0 + 12);
        float4 b0 = *reinterpret_cast<const float4*>(bg + k0);
        float4 b1 = *reinterpret_cast<const float4*>(bg + k0 + 8);

        __syncthreads();

        half8 ha0, ha1;
        ha0[0] = (_Float16)a0.x; ha0[1] = (_Float16)a0.y; ha0[2] = (_Float16)a0.z; ha0[3] = (_Float16)a0.w;
        ha0[4] = (_Float16)a1.x; ha0[5] = (_Float16)a1.y; ha0[6] = (_Float16)a1.z; ha0[7] = (_Float16)a1.w;
        ha1[0] = (_Float16)a2.x; ha1[1] = (_Float16)a2.y; ha1[2] = (_Float16)a2.z; ha1[3] = (_Float16)a2.w;
        ha1[4] = (_Float16)a3.x; ha1[5] = (_Float16)a3.y; ha1[6] = (_Float16)a3.z; ha1[7] = (_Float16)a3.w;
        *reinterpret_cast<half8*>(aw)     = ha0;
        *reinterpret_cast<half8*>(aw + 8) = ha1;
        *reinterpret_cast<float4*>(bw)     = b0;
        *reinterpret_cast<float4*>(bw + 8) = b1;

        __syncthreads();

        half8 af[4], bf[4];
#pragma unroll
        for (int i = 0; i < 4; i++) {
            af[i] = *reinterpret_cast<const half8*>(&As[(wm + i * 16 + l16) * LDA + quad * 8]);
            bf[i] = *reinterpret_cast<const half8*>(&Bs[(wn + i * 16 + l16) * LDA + quad * 8]);
        }
#pragma unroll
        for (int mi = 0; mi < 4; mi++)
#pragma unroll
            for (int ni = 0; ni < 4; ni++)
                acc[mi][ni] = __builtin_amdgcn_mfma_f32_16x16x32_f16(af[mi], bf[ni], acc[mi][ni], 0, 0, 0);
    }

    const int bidx = m0 >> 10;
    float qv[4], vv[4];
#pragma unroll
    for (int ni = 0; ni < 4; ni++) {
        int g = n0 + wn + ni * 16 + l16;
        qv[ni] = q[bidx * HDIM + g];
        vv[ni] = v[g];
    }
#pragma unroll
    for (int mi = 0; mi < 4; mi++) {
#pragma unroll
        for (int r = 0; r < 4; r++) {
            int row = wm + mi * 16 + quad * 4 + r;
            float s = 0.f;
#pragma unroll
            for (int ni = 0; ni < 4; ni++) {
                float pre = acc[mi][ni][r] + qv[ni];
                float e = __expf(2.f * pre);
                float th = 1.f - 2.f / (e + 1.f);
                s = fmaf(th, vv[ni], s);
            }
            s += __shfl_xor(s, 1);
            s += __shfl_xor(s, 2);
            s += __shfl_xor(s, 4);
            s += __shfl_xor(s, 8);
            if (l16 == 0) atomicAdd(&energies[m0 + row], s);
        }
    }
}

// ---------------- softmax over t per batch row ----------------
__global__ void softmax_k(const float* __restrict__ energies, float* __restrict__ out) {
    int b = blockIdx.x;
    int t = threadIdx.x;
    int wave = t >> 6, lane = t & 63;
    __shared__ float smax[4], ssum[4];
    float e[4];
#pragma unroll
    for (int i = 0; i < 4; i++) e[i] = energies[b * TLEN + t + i * 256];
    float m = fmaxf(fmaxf(e[0], e[1]), fmaxf(e[2], e[3]));
#pragma unroll
    for (int off = 32; off >= 1; off >>= 1) m = fmaxf(m, __shfl_xor(m, off));
    if (lane == 0) smax[wave] = m;
    __syncthreads();
    float M = fmaxf(fmaxf(smax[0], smax[1]), fmaxf(smax[2], smax[3]));
    float x[4]; float s = 0.f;
#pragma unroll
    for (int i = 0; i < 4; i++) { x[i] = __expf(e[i] - M); s += x[i]; }
#pragma unroll
    for (int off = 32; off >= 1; off >>= 1) s += __shfl_xor(s, off);
    if (lane == 0) ssum[wave] = s;
    __syncthreads();
    float S = ssum[0] + ssum[1] + ssum[2] + ssum[3];
    float inv = 1.f / S;
#pragma unroll
    for (int i = 0; i < 4; i++) out[b * TLEN + t + i * 256] = x[i] * inv;
}

extern "C" void kernel_launch(void* const* d_in, const int* in_sizes, int n_in,
                              void* d_out, int out_size, void* d_ws, size_t ws_size,
                              hipStream_t stream) {
    const float* hidden = (const float*)d_in[0];   // (1, 32, 1024) fp32
    const float* enc    = (const float*)d_in[1];   // (32, 1024, 1024) fp32
    const float* W      = (const float*)d_in[2];   // (1024, 2048) fp32
    const float* bias   = (const float*)d_in[3];   // (1024,) fp32
    const float* v      = (const float*)d_in[4];   // (1024,) fp32
    float* out = (float*)d_out;                    // (32, 1, 1024) fp32

    char* ws = (char*)d_ws;
    float*    q     = (float*)ws;                  // 128 KB
    float*    energ = (float*)(ws + 131072);       // 128 KB
    _Float16* We16  = (_Float16*)(ws + 262144);    // 2 MB
    _Float16* enc16 = (_Float16*)(ws + 262144 + 2097152);  // 64 MB
    const size_t need_fast = 262144 + 2097152 + (size_t)M_TOT * HDIM * 2;  // ~66.3 MB

    zero_k<<<dim3(M_TOT / 256), 256, 0, stream>>>(energ);
    we_convert_k<<<dim3(1024), 256, 0, stream>>>(W, We16);
    qproj_k<<<dim3(HDIM), 256, 0, stream>>>(hidden, W, bias, q);
    if (ws_size >= need_fast) {
        enc_convert_k<<<dim3((size_t)M_TOT * HDIM / 8 / 256), 256, 0, stream>>>(enc, enc16);
        attn_gemm_lds_k<<<dim3(256, 8), 256, 0, stream>>>(enc16, We16, q, v, energ);
    } else {
        attn_gemm_k<<<dim3(256, 8), 256, 0, stream>>>(enc, We16, q, v, energ);
    }
    softmax_k<<<dim3(BATCH), 256, 0, stream>>>(energ, out);
}

// Round 4
// 317.606 us; speedup vs baseline: 1.0744x; 1.0000x over previous
//
#include <hip/hip_runtime.h>
#include <hip/hip_fp16.h>

typedef _Float16 half8   __attribute__((ext_vector_type(8)));
typedef _Float16 half4_t __attribute__((ext_vector_type(4)));
typedef float    f32x4   __attribute__((ext_vector_type(4)));

#define HDIM  1024
#define BATCH 32
#define TLEN  1024
#define M_TOT (BATCH * TLEN)

#define BM 128
#define BN 128
#define BKF 64   // fast-path K-tile (halves); row = 128 B
#define LDA 40   // fallback-path padded LDS stride (halves)

// ---------------- fused prep: We16 convert (blocks 0..1023), qproj (1024..2047), zero (2048..2175)
__global__ void prep_k(const float* __restrict__ W, const float* __restrict__ hidden,
                       const float* __restrict__ bias, _Float16* __restrict__ We16,
                       float* __restrict__ q, float* __restrict__ energ) {
    const int bid = blockIdx.x;
    const int t = threadIdx.x;
    if (bid < 1024) {
        // We = W[:, H:] -> fp16, g-major k-contiguous
        int idx = bid * 256 + t;               // [0, 1024*1024/4)
        int g  = idx >> 8;
        int k4 = idx & 255;
        float4 f = *reinterpret_cast<const float4*>(W + (size_t)g * 2048 + 1024 + k4 * 4);
        half4_t h;
        h[0] = (_Float16)f.x; h[1] = (_Float16)f.y; h[2] = (_Float16)f.z; h[3] = (_Float16)f.w;
        *reinterpret_cast<half4_t*>(We16 + (size_t)idx * 4) = h;
    } else if (bid < 2048) {
        // q[b][g] = bias[g] + sum_h hidden[b][h] * W[g][h]
        int g = bid - 1024;
        int wave = t >> 6, lane = t & 63;
        float acc[BATCH];
#pragma unroll
        for (int b = 0; b < BATCH; b++) acc[b] = 0.f;
        const float* wr = W + (size_t)g * 2048;
        for (int h = t; h < HDIM; h += 256) {
            float w = wr[h];
#pragma unroll
            for (int b = 0; b < BATCH; b++) acc[b] = fmaf(w, hidden[b * HDIM + h], acc[b]);
        }
        __shared__ float sm[4 * BATCH];
#pragma unroll
        for (int b = 0; b < BATCH; b++) {
            float s = acc[b];
#pragma unroll
            for (int off = 32; off >= 1; off >>= 1) s += __shfl_xor(s, off);
            if (lane == 0) sm[wave * BATCH + b] = s;
        }
        __syncthreads();
        if (t < BATCH) {
            float s = sm[t] + sm[BATCH + t] + sm[2 * BATCH + t] + sm[3 * BATCH + t];
            q[t * HDIM + g] = s + bias[g];
        }
    } else {
        energ[(bid - 2048) * 256 + t] = 0.f;
    }
}

// ---------------- convert enc (32M fp32) to fp16 ----------------
__global__ void enc_convert_k(const float* __restrict__ enc, _Float16* __restrict__ enc16) {
    size_t i = ((size_t)blockIdx.x * blockDim.x + threadIdx.x) * 8;
    float4 f0 = *reinterpret_cast<const float4*>(enc + i);
    float4 f1 = *reinterpret_cast<const float4*>(enc + i + 4);
    half8 h;
    h[0] = (_Float16)f0.x; h[1] = (_Float16)f0.y; h[2] = (_Float16)f0.z; h[3] = (_Float16)f0.w;
    h[4] = (_Float16)f1.x; h[5] = (_Float16)f1.y; h[6] = (_Float16)f1.z; h[7] = (_Float16)f1.w;
    *reinterpret_cast<half8*>(enc16 + i) = h;
}

__device__ __forceinline__ void async16(const void* g, void* l) {
    __builtin_amdgcn_global_load_lds(
        (const __attribute__((address_space(1))) void*)g,
        (__attribute__((address_space(3))) void*)l, 16, 0, 0);
}

// ---------------- FAST: BK=64, XOR-swizzled LDS, issue-early pipeline, XCD-aware remap ----
// 1D grid 2048. xcd = id&7 (dispatch %8 round-robin); each XCD owns 32 m-stripes;
// the 8 n-blocks of a stripe are dispatch-adjacent within the XCD -> stripe read once into L2.
__global__ __launch_bounds__(256)
void attn_gemm_lds_k(const _Float16* __restrict__ enc16,
                     const _Float16* __restrict__ We16,
                     const float* __restrict__ q, const float* __restrict__ v,
                     float* __restrict__ energies) {
    __shared__ _Float16 As[BM * BKF];   // 16 KB, rows of 128 B, chunks XOR-swizzled
    __shared__ _Float16 Bs[BN * BKF];   // 16 KB

    const int tid  = threadIdx.x;
    const int id   = blockIdx.x;
    const int xcd  = id & 7;
    const int w    = id >> 3;
    const int m0   = (xcd * 32 + (w >> 3)) * BM;
    const int n0   = (w & 7) * BN;
    const int wave = tid >> 6;
    const int lane = tid & 63;
    const int quad = lane >> 4;
    const int l16  = lane & 15;
    const int wm   = (wave & 1) * 64;
    const int wn   = (wave >> 1) * 64;

    f32x4 acc[4][4];
#pragma unroll
    for (int i = 0; i < 4; i++)
#pragma unroll
        for (int j = 0; j < 4; j++) acc[i][j] = {0.f, 0.f, 0.f, 0.f};

    // staging: issue ii covers rows wave*32+ii*8 + (lane>>3); fetched chunk c=(lane&7)^(lane>>3)
    const int srow = wave * 32 + (lane >> 3);
    const int scol = ((lane & 7) ^ (lane >> 3)) * 8;          // halves
    const _Float16* gA = enc16 + (size_t)(m0 + srow) * HDIM + scol;
    const _Float16* gB = We16  + (size_t)(n0 + srow) * HDIM + scol;
    _Float16* lA = As + wave * 2048;
    _Float16* lB = Bs + wave * 2048;
    const size_t istep = (size_t)8 * HDIM;

#pragma unroll
    for (int ii = 0; ii < 4; ii++) {
        async16(gA + ii * istep, lA + ii * 512);
        async16(gB + ii * istep, lB + ii * 512);
    }
    __syncthreads();

    // frag read offsets: row r wants chunk c=s*4+quad, stored at c^(r&7)
    int aoff[2][4], boff[2][4];
#pragma unroll
    for (int s = 0; s < 2; s++)
#pragma unroll
        for (int i = 0; i < 4; i++) {
            int ra = wm + i * 16 + l16;
            int rb = wn + i * 16 + l16;
            aoff[s][i] = ra * BKF + (((s * 4 + quad) ^ (l16 & 7)) * 8);
            boff[s][i] = rb * BKF + (((s * 4 + quad) ^ (l16 & 7)) * 8);
        }

    for (int k0 = 0; k0 < HDIM; k0 += BKF) {
        half8 af[2][4], bf[2][4];
#pragma unroll
        for (int s = 0; s < 2; s++)
#pragma unroll
            for (int i = 0; i < 4; i++) {
                af[s][i] = *reinterpret_cast<const half8*>(&As[aoff[s][i]]);
                bf[s][i] = *reinterpret_cast<const half8*>(&Bs[boff[s][i]]);
            }
        __syncthreads();   // all waves done reading LDS

        if (k0 + BKF < HDIM) {
            const int kn = k0 + BKF;
#pragma unroll
            for (int ii = 0; ii < 4; ii++) {
                async16(gA + kn + ii * istep, lA + ii * 512);
                async16(gB + kn + ii * istep, lB + ii * 512);
            }
        }

#pragma unroll
        for (int s = 0; s < 2; s++)
#pragma unroll
            for (int mi = 0; mi < 4; mi++)
#pragma unroll
                for (int ni = 0; ni < 4; ni++)
                    acc[mi][ni] = __builtin_amdgcn_mfma_f32_16x16x32_f16(af[s][mi], bf[s][ni], acc[mi][ni], 0, 0, 0);

        __syncthreads();   // drains vmcnt -> next tile valid
    }

    // epilogue: C/D col = l16, row = quad*4 + r
    const int bidx = m0 >> 10;
    float qv[4], vv[4];
#pragma unroll
    for (int ni = 0; ni < 4; ni++) {
        int g = n0 + wn + ni * 16 + l16;
        qv[ni] = q[bidx * HDIM + g];
        vv[ni] = v[g];
    }
#pragma unroll
    for (int mi = 0; mi < 4; mi++) {
#pragma unroll
        for (int r = 0; r < 4; r++) {
            int row = wm + mi * 16 + quad * 4 + r;
            float s = 0.f;
#pragma unroll
            for (int ni = 0; ni < 4; ni++) {
                float pre = acc[mi][ni][r] + qv[ni];
                float e = __expf(2.f * pre);
                float th = 1.f - 2.f / (e + 1.f);
                s = fmaf(th, vv[ni], s);
            }
            s += __shfl_xor(s, 1);
            s += __shfl_xor(s, 2);
            s += __shfl_xor(s, 4);
            s += __shfl_xor(s, 8);
            if (l16 == 0) atomicAdd(&energies[m0 + row], s);
        }
    }
}

// ---------------- FALLBACK: fp32 A on-the-fly convert (BK=32, padded LDS) ----------------
__global__ __launch_bounds__(256, 2)
void attn_gemm_k(const float* __restrict__ enc, const _Float16* __restrict__ We16,
                 const float* __restrict__ q, const float* __restrict__ v,
                 float* __restrict__ energies) {
    __shared__ _Float16 As[BM * LDA];
    __shared__ _Float16 Bs[BN * LDA];

    const int tid  = threadIdx.x;
    const int m0   = blockIdx.x * BM;
    const int n0   = blockIdx.y * BN;
    const int wave = tid >> 6;
    const int lane = tid & 63;
    const int quad = lane >> 4;
    const int l16  = lane & 15;
    const int wm   = (wave & 1) * 64;
    const int wn   = (wave >> 1) * 64;

    const int srow = tid >> 1;
    const int scol = (tid & 1) * 16;

    f32x4 acc[4][4];
#pragma unroll
    for (int i = 0; i < 4; i++)
#pragma unroll
        for (int j = 0; j < 4; j++) acc[i][j] = {0.f, 0.f, 0.f, 0.f};

    const float*    ag = enc  + (size_t)(m0 + srow) * HDIM + scol;
    const _Float16* bg = We16 + (size_t)(n0 + srow) * HDIM + scol;
    _Float16* aw = &As[srow * LDA + scol];
    _Float16* bw = &Bs[srow * LDA + scol];

    for (int k0 = 0; k0 < HDIM; k0 += 32) {
        float4 a0 = *reinterpret_cast<const float4*>(ag + k0 + 0);
        float4 a1 = *reinterpret_cast<const float4*>(ag + k0 + 4);
        float4 a2 = *reinterpret_cast<const float4*>(ag + k0 + 8);
        float4 a3 = *reinterpret_cast<const float4*>(ag + k0 + 12);
        float4 b0 = *reinterpret_cast<const float4*>(bg + k0);
        float4 b1 = *reinterpret_cast<const float4*>(bg + k0 + 8);

        __syncthreads();

        half8 ha0, ha1;
        ha0[0] = (_Float16)a0.x; ha0[1] = (_Float16)a0.y; ha0[2] = (_Float16)a0.z; ha0[3] = (_Float16)a0.w;
        ha0[4] = (_Float16)a1.x; ha0[5] = (_Float16)a1.y; ha0[6] = (_Float16)a1.z; ha0[7] = (_Float16)a1.w;
        ha1[0] = (_Float16)a2.x; ha1[1] = (_Float16)a2.y; ha1[2] = (_Float16)a2.z; ha1[3] = (_Float16)a2.w;
        ha1[4] = (_Float16)a3.x; ha1[5] = (_Float16)a3.y; ha1[6] = (_Float16)a3.z; ha1[7] = (_Float16)a3.w;
        *reinterpret_cast<half8*>(aw)     = ha0;
        *reinterpret_cast<half8*>(aw + 8) = ha1;
        *reinterpret_cast<float4*>(bw)     = b0;
        *reinterpret_cast<float4*>(bw + 8) = b1;

        __syncthreads();

        half8 af[4], bf[4];
#pragma unroll
        for (int i = 0; i < 4; i++) {
            af[i] = *reinterpret_cast<const half8*>(&As[(wm + i * 16 + l16) * LDA + quad * 8]);
            bf[i] = *reinterpret_cast<const half8*>(&Bs[(wn + i * 16 + l16) * LDA + quad * 8]);
        }
#pragma unroll
        for (int mi = 0; mi < 4; mi++)
#pragma unroll
            for (int ni = 0; ni < 4; ni++)
                acc[mi][ni] = __builtin_amdgcn_mfma_f32_16x16x32_f16(af[mi], bf[ni], acc[mi][ni], 0, 0, 0);
    }

    const int bidx = m0 >> 10;
    float qv[4], vv[4];
#pragma unroll
    for (int ni = 0; ni < 4; ni++) {
        int g = n0 + wn + ni * 16 + l16;
        qv[ni] = q[bidx * HDIM + g];
        vv[ni] = v[g];
    }
#pragma unroll
    for (int mi = 0; mi < 4; mi++) {
#pragma unroll
        for (int r = 0; r < 4; r++) {
            int row = wm + mi * 16 + quad * 4 + r;
            float s = 0.f;
#pragma unroll
            for (int ni = 0; ni < 4; ni++) {
                float pre = acc[mi][ni][r] + qv[ni];
                float e = __expf(2.f * pre);
                float th = 1.f - 2.f / (e + 1.f);
                s = fmaf(th, vv[ni], s);
            }
            s += __shfl_xor(s, 1);
            s += __shfl_xor(s, 2);
            s += __shfl_xor(s, 4);
            s += __shfl_xor(s, 8);
            if (l16 == 0) atomicAdd(&energies[m0 + row], s);
        }
    }
}

// ---------------- softmax over t per batch row ----------------
__global__ void softmax_k(const float* __restrict__ energies, float* __restrict__ out) {
    int b = blockIdx.x;
    int t = threadIdx.x;
    int wave = t >> 6, lane = t & 63;
    __shared__ float smax[4], ssum[4];
    float e[4];
#pragma unroll
    for (int i = 0; i < 4; i++) e[i] = energies[b * TLEN + t + i * 256];
    float m = fmaxf(fmaxf(e[0], e[1]), fmaxf(e[2], e[3]));
#pragma unroll
    for (int off = 32; off >= 1; off >>= 1) m = fmaxf(m, __shfl_xor(m, off));
    if (lane == 0) smax[wave] = m;
    __syncthreads();
    float M = fmaxf(fmaxf(smax[0], smax[1]), fmaxf(smax[2], smax[3]));
    float x[4]; float s = 0.f;
#pragma unroll
    for (int i = 0; i < 4; i++) { x[i] = __expf(e[i] - M); s += x[i]; }
#pragma unroll
    for (int off = 32; off >= 1; off >>= 1) s += __shfl_xor(s, off);
    if (lane == 0) ssum[wave] = s;
    __syncthreads();
    float S = ssum[0] + ssum[1] + ssum[2] + ssum[3];
    float inv = 1.f / S;
#pragma unroll
    for (int i = 0; i < 4; i++) out[b * TLEN + t + i * 256] = x[i] * inv;
}

extern "C" void kernel_launch(void* const* d_in, const int* in_sizes, int n_in,
                              void* d_out, int out_size, void* d_ws, size_t ws_size,
                              hipStream_t stream) {
    const float* hidden = (const float*)d_in[0];   // (1, 32, 1024) fp32
    const float* enc    = (const float*)d_in[1];   // (32, 1024, 1024) fp32
    const float* W      = (const float*)d_in[2];   // (1024, 2048) fp32
    const float* bias   = (const float*)d_in[3];   // (1024,) fp32
    const float* v      = (const float*)d_in[4];   // (1024,) fp32
    float* out = (float*)d_out;                    // (32, 1, 1024) fp32

    char* ws = (char*)d_ws;
    float*    q     = (float*)ws;                  // 128 KB
    float*    energ = (float*)(ws + 131072);       // 128 KB
    _Float16* We16  = (_Float16*)(ws + 262144);    // 2 MB
    _Float16* enc16 = (_Float16*)(ws + 262144 + 2097152);  // 64 MB
    const size_t need_fast = 262144 + 2097152 + (size_t)M_TOT * HDIM * 2;  // ~66.3 MB

    // prep: blocks 0..1023 we_convert, 1024..2047 qproj, 2048..2175 zero energies
    prep_k<<<dim3(2176), 256, 0, stream>>>(W, hidden, bias, We16, q, energ);
    if (ws_size >= need_fast) {
        enc_convert_k<<<dim3((size_t)M_TOT * HDIM / 8 / 256), 256, 0, stream>>>(enc, enc16);
        attn_gemm_lds_k<<<dim3(2048), 256, 0, stream>>>(enc16, We16, q, v, energ);
    } else {
        attn_gemm_k<<<dim3(256, 8), 256, 0, stream>>>(enc, We16, q, v, energ);
    }
    softmax_k<<<dim3(BATCH), 256, 0, stream>>>(energ, out);
}